// Round 3
// baseline (198.598 us; speedup 1.0000x reference)
//
#include <hip/hip_runtime.h>

typedef _Float16 v8h __attribute__((ext_vector_type(8)));
typedef float v16f __attribute__((ext_vector_type(16)));

// ---------------------------------------------------------------------------
// BF: B in MFMA-fragment order, padded to 66 ko (pad rows = 0).
// Fragment f = kk16*2 + nf holds at [lane*8 + j]:
//   B[k = kk16*16 + (lane>>5)*8 + j][o = nf*32 + (lane&31)]
// where B[k][o] = (ko<64) ? w2[ko, i*64+o] : (ko==64 ? b2[i*64+o] : 0),
// ko = k/IN, i = k%IN. kk16 = ko*PH + p.
//
// prep_fused also computes agg0 = bias0 + x@root0 and emits x in f16.
// ---------------------------------------------------------------------------
__global__ void prep_fused(const float* __restrict__ w2_0, const float* __restrict__ b2_0,
                           _Float16* __restrict__ BF0,
                           const float* __restrict__ w2_1, const float* __restrict__ b2_1,
                           _Float16* __restrict__ BF1,
                           const float* __restrict__ x, const float* __restrict__ root,
                           const float* __restrict__ bias, float* __restrict__ agg,
                           _Float16* __restrict__ xb, int N) {
    int idx = blockIdx.x * 256 + threadIdx.x;
    const int n0 = 264 * 512;   // layer0: 66 ko * 2 kk16/ko * 2 nf
    const int n1 = 528 * 512;   // layer1: 66 ko * 4 kk16/ko * 2 nf
    if (idx < n0 + n1) {
        const float* w2; const float* b2; _Float16* BF; int IN, rel;
        if (idx < n0) { w2 = w2_0; b2 = b2_0; BF = BF0; IN = 32; rel = idx; }
        else          { w2 = w2_1; b2 = b2_1; BF = BF1; IN = 64; rel = idx - n0; }
        int j = rel & 7, lane = (rel >> 3) & 63, f = rel >> 9;
        int nf = f & 1, kk16 = f >> 1;
        int ln = lane & 31, g2 = lane >> 5;
        int k = kk16 * 16 + g2 * 8 + j;
        int ko = k / IN, i = k - ko * IN;
        int o = nf * 32 + ln;
        float v = (ko < 64) ? w2[ko * (IN * 64) + i * 64 + o]
                : (ko == 64 ? b2[i * 64 + o] : 0.f);
        BF[rel] = (_Float16)v;
        return;
    }
    idx -= (n0 + n1);
    if (idx >= N * 64) return;
    int n = idx >> 6, o = idx & 63;
    float s = bias[o];
    const float* xr = x + (size_t)n * 32;
    #pragma unroll 8
    for (int i = 0; i < 32; ++i) s += xr[i] * root[i * 64 + o];
    agg[idx] = s;
    if (o < 32) xb[n * 32 + o] = (_Float16)xr[o];
}

// x1b = f16(relu(agg0)); agg1[n,o] = bias1[o] + sum_i relu(agg0[n,i])*root1[i,o]
__global__ void mid_kernel(const float* __restrict__ agg0, const float* __restrict__ root1,
                           const float* __restrict__ bias1, _Float16* __restrict__ x1b,
                           float* __restrict__ agg1, int N) {
    int idx = blockIdx.x * 256 + threadIdx.x;
    if (idx >= N * 64) return;
    int n = idx >> 6, o = idx & 63;
    const float* ar = agg0 + (size_t)n * 64;
    float s = bias1[o];
    #pragma unroll 8
    for (int i = 0; i < 64; ++i) s += fmaxf(ar[i], 0.f) * root1[i * 64 + o];
    agg1[idx] = s;
    x1b[idx] = (_Float16)fmaxf(agg0[idx], 0.f);
}

__global__ void final_relu(const float* __restrict__ agg1, float* __restrict__ out, int n) {
    int idx = blockIdx.x * 256 + threadIdx.x;
    if (idx < n) out[idx] = fmaxf(agg1[idx], 0.f);
}

// ---------------------------------------------------------------------------
// Edge GEMM v8: 96-edge tile (521 blocks = 2.03 x 256 CUs -> even 2-round
// schedule, no half-idle tail), 4 waves. Wave w owns nf = w&1, K-half = w>>1,
// and all THREE m-slices. Each B fragment is read by exactly ONE wave -> no
// barrier / no LDS staging in the K-loop. B streams L2->reg through a
// 3-buffer, lookahead-2, statically-indexed pipeline (covers ~2 FM bodies
// ~ 300+ cyc vs ~200 cyc L2 latency); sh_r1 scales are prefetched one ko
// ahead the same way. The K-half combine buffer OVERLAYS sh_x/sh_r1 (dead
// after the K-loop; extra barrier makes it safe) -> LDS ~25 KB, so 2 blocks
// co-reside per CU even at high VGPR. One global atomic per output element.
// ---------------------------------------------------------------------------
template<int IN_C>
__global__ __launch_bounds__(256, 2)
void edge_gemm(const float* __restrict__ ea,
               const float* __restrict__ w1, const float* __restrict__ b1,
               const _Float16* __restrict__ xb, const _Float16* __restrict__ BF,
               const int* __restrict__ srcI, const int* __restrict__ dstI,
               float* __restrict__ agg, int E) {
    constexpr int PH  = IN_C / 16;        // fragments per ko per nf
    constexpr int CPR = IN_C / 8;         // 16B chunks per x row
    constexpr int M   = 96;               // edges per block

    constexpr size_t XBYTES = (size_t)M * IN_C * 2;     // sh_x
    constexpr size_t RBYTES = (size_t)M * 66 * 2;       // sh_r1
    constexpr size_t BBYTES = (size_t)M * 65 * 4;       // reduction buf
    constexpr size_t SBYTES = (XBYTES + RBYTES > BBYTES) ? (XBYTES + RBYTES) : BBYTES;

    __shared__ __align__(16) char smem[SBYTES];
    __shared__ int sh_dst[M];
    auto sh_x  = (_Float16 (*)[IN_C])smem;              // live: prologue..K-loop
    auto sh_r1 = (_Float16 (*)[66])(smem + XBYTES);     // live: prologue..K-loop
    auto buf   = (float (*)[65])smem;                   // live: after 2nd barrier

    int tid = threadIdx.x;
    int ebase = blockIdx.x * M;
    int valid = E - ebase; if (valid > M) valid = M;

    if (tid < M) {
        sh_dst[tid] = (tid < valid) ? dstI[ebase + tid] : 0;
        sh_r1[tid][64] = (_Float16)1.f;   // scale 1 for the b2 row of BF
        sh_r1[tid][65] = (_Float16)0.f;   // scale 0 for the zero-pad row
    }
    // r1 tile computed in-kernel: relu(ea @ w1 + b1)
    for (int i = tid; i < M * 64; i += 256) {
        int e = i >> 6, j = i & 63;
        int ge = (e < valid) ? (ebase + e) : ebase;
        float2 av = *(const float2*)(ea + (size_t)ge * 2);
        sh_r1[e][j] = (_Float16)fmaxf(av.x * w1[j] + av.y * w1[64 + j] + b1[j], 0.f);
    }
    // gathered x tile
    for (int i = tid; i < M * CPR; i += 256) {
        int r = i / CPR, c = i - r * CPR;
        int sidx = (r < valid) ? srcI[ebase + r] : 0;
        *(uint4*)&sh_x[r][c * 8] = *(const uint4*)(xb + (size_t)sidx * IN_C + (size_t)c * 8);
    }
    __syncthreads();

    int wv = tid >> 6, lane = tid & 63, ln = lane & 31, g2 = lane >> 5;
    int nf = wv & 1, kh = wv >> 1;

    // x slices for the three m-slices (rows ln, ln+32, ln+64)
    v8h xs0[PH], xs1[PH], xs2[PH];
    #pragma unroll
    for (int p = 0; p < PH; ++p) {
        xs0[p] = *(const v8h*)&sh_x[ln     ][p * 16 + g2 * 8];
        xs1[p] = *(const v8h*)&sh_x[ln + 32][p * 16 + g2 * 8];
        xs2[p] = *(const v8h*)&sh_x[ln + 64][p * 16 + g2 * 8];
    }

    v16f acc0 = {0,0,0,0,0,0,0,0,0,0,0,0,0,0,0,0};
    v16f acc1 = acc0, acc2 = acc0;

    // wave's fragment stream: frag(ko,p) at uint4 index (ko*PH+p)*128 + nf*64 + lane
    const uint4* bp = (const uint4*)BF + (size_t)nf * 64 + lane;
    int kb = kh * 33;                     // 33 ko per K-half (66 total incl bias+pad)

    uint4 b0[PH], b1v[PH], b2v[PH];       // 3 static buffers, lookahead-2
    _Float16 s0[3], s1[3], s2[3];

    auto LD = [&](uint4 (&d)[PH], int ko) {
        #pragma unroll
        for (int p = 0; p < PH; ++p) d[p] = bp[(size_t)(ko * PH + p) * 128];
    };
    auto SV = [&](_Float16 (&s)[3], int ko) {
        s[0] = sh_r1[ln     ][ko];
        s[1] = sh_r1[ln + 32][ko];
        s[2] = sh_r1[ln + 64][ko];
    };
    auto FM = [&](uint4 (&d)[PH], _Float16 (&s)[3]) {
        #pragma unroll
        for (int p = 0; p < PH; ++p) {
            v8h bb; __builtin_memcpy(&bb, &d[p], 16);
            acc0 = __builtin_amdgcn_mfma_f32_32x32x16_f16(xs0[p] * s[0], bb, acc0, 0, 0, 0);
            acc1 = __builtin_amdgcn_mfma_f32_32x32x16_f16(xs1[p] * s[1], bb, acc1, 0, 0, 0);
            acc2 = __builtin_amdgcn_mfma_f32_32x32x16_f16(xs2[p] * s[2], bb, acc2, 0, 0, 0);
        }
    };

    LD(b0, kb);     SV(s0, kb);
    LD(b1v, kb + 1); SV(s1, kb + 1);
    #pragma unroll 1
    for (int t = 0; t < 30; t += 3) {     // FMs cover ko kb..kb+29
        LD(b2v, kb + t + 2); SV(s2, kb + t + 2); FM(b0,  s0);
        LD(b0,  kb + t + 3); SV(s0, kb + t + 3); FM(b1v, s1);
        LD(b1v, kb + t + 4); SV(s1, kb + t + 4); FM(b2v, s2);
    }
    LD(b2v, kb + 32); SV(s2, kb + 32);    // max ko touched = kb+32 (<=65)
    FM(b0, s0); FM(b1v, s1); FM(b2v, s2); // ko kb+30..kb+32

    // ---- combine K-halves. buf overlays sh_x/sh_r1: barrier first so every
    // wave is done reading them, then kh=1 stores, barrier, kh=0 adds+atomics.
    int colb = nf * 32 + ln;
    __syncthreads();
    if (kh == 1) {
        #pragma unroll
        for (int r = 0; r < 16; ++r) {
            int row = 4 * g2 + (r & 3) + 8 * (r >> 2);
            buf[row     ][colb] = acc0[r];
            buf[row + 32][colb] = acc1[r];
            buf[row + 64][colb] = acc2[r];
        }
    }
    __syncthreads();
    if (kh == 0) {
        #pragma unroll
        for (int r = 0; r < 16; ++r) {
            int row = 4 * g2 + (r & 3) + 8 * (r >> 2);
            if (row < valid)
                atomicAdd(&agg[(size_t)sh_dst[row] * 64 + colb], acc0[r] + buf[row][colb]);
            int row1 = row + 32;
            if (row1 < valid)
                atomicAdd(&agg[(size_t)sh_dst[row1] * 64 + colb], acc1[r] + buf[row1][colb]);
            int row2 = row + 64;
            if (row2 < valid)
                atomicAdd(&agg[(size_t)sh_dst[row2] * 64 + colb], acc2[r] + buf[row2][colb]);
        }
    }
}

// ---------------------------------------------------------------------------
extern "C" void kernel_launch(void* const* d_in, const int* in_sizes, int n_in,
                              void* d_out, int out_size, void* d_ws, size_t ws_size,
                              hipStream_t stream) {
    const float* x      = (const float*)d_in[0];
    const int*   ei     = (const int*)d_in[1];
    const float* ea     = (const float*)d_in[2];
    const float* w1_0   = (const float*)d_in[3];
    const float* b1_0   = (const float*)d_in[4];
    const float* w2_0   = (const float*)d_in[5];
    const float* b2_0   = (const float*)d_in[6];
    const float* root_0 = (const float*)d_in[7];
    const float* bias_0 = (const float*)d_in[8];
    const float* w1_1   = (const float*)d_in[9];
    const float* b1_1   = (const float*)d_in[10];
    const float* w2_1   = (const float*)d_in[11];
    const float* b2_1   = (const float*)d_in[12];
    const float* root_1 = (const float*)d_in[13];
    const float* bias_1 = (const float*)d_in[14];
    float* out = (float*)d_out;

    int N = in_sizes[0] / 32;
    int E = in_sizes[1] / 2;
    const int* srcI = ei;
    const int* dstI = ei + E;

    char* ws = (char*)d_ws;
    size_t off = 0;
    auto carve = [&](size_t bytes) {
        void* p = ws + off;
        off += (bytes + 255) & ~(size_t)255;
        return p;
    };
    _Float16* BF0  = (_Float16*)carve((size_t)264 * 512 * 2);
    _Float16* BF1  = (_Float16*)carve((size_t)528 * 512 * 2);
    _Float16* XB0  = (_Float16*)carve((size_t)N * 32 * 2);
    _Float16* X1B  = (_Float16*)carve((size_t)N * 64 * 2);
    float*    AGG0 = (float*)carve((size_t)N * 64 * 4);
    float*    AGG1 = (float*)carve((size_t)N * 64 * 4);

    int tprep = (264 + 528) * 512 + N * 64;
    prep_fused<<<(tprep + 255) / 256, 256, 0, stream>>>(w2_0, b2_0, BF0, w2_1, b2_1, BF1,
                                                        x, root_0, bias_0, AGG0, XB0, N);

    int gblocks = (E + 95) / 96;
    edge_gemm<32><<<gblocks, 256, 0, stream>>>(ea, w1_0, b1_0, XB0, BF0, srcI, dstI, AGG0, E);

    mid_kernel<<<(N * 64 + 255) / 256, 256, 0, stream>>>(AGG0, root_1, bias_1, X1B, AGG1, N);

    edge_gemm<64><<<gblocks, 256, 0, stream>>>(ea, w1_1, b1_1, X1B, BF1, srcI, dstI, AGG1, E);

    final_relu<<<(N * 64 + 255) / 256, 256, 0, stream>>>(AGG1, out, N * 64);
}

// Round 4
// 193.174 us; speedup vs baseline: 1.0281x; 1.0281x over previous
//
#include <hip/hip_runtime.h>

typedef _Float16 v8h __attribute__((ext_vector_type(8)));
typedef float v16f __attribute__((ext_vector_type(16)));

// ---------------------------------------------------------------------------
// BF: B in MFMA-fragment order, padded to 66 ko (pad rows = 0).
// Fragment f = kk16*2 + nf holds at [lane*8 + j]:
//   B[k = kk16*16 + (lane>>5)*8 + j][o = nf*32 + (lane&31)]
// where B[k][o] = (ko<64) ? w2[ko, i*64+o] : (ko==64 ? b2[i*64+o] : 0),
// ko = k/IN, i = k%IN. kk16 = ko*PH + p.
//
// prep_fused also computes agg0 = bias0 + x@root0 and emits x in f16.
// ---------------------------------------------------------------------------
__global__ void prep_fused(const float* __restrict__ w2_0, const float* __restrict__ b2_0,
                           _Float16* __restrict__ BF0,
                           const float* __restrict__ w2_1, const float* __restrict__ b2_1,
                           _Float16* __restrict__ BF1,
                           const float* __restrict__ x, const float* __restrict__ root,
                           const float* __restrict__ bias, float* __restrict__ agg,
                           _Float16* __restrict__ xb, int N) {
    int idx = blockIdx.x * 256 + threadIdx.x;
    const int n0 = 264 * 512;   // layer0: 66 ko * 2 kk16/ko * 2 nf
    const int n1 = 528 * 512;   // layer1: 66 ko * 4 kk16/ko * 2 nf
    if (idx < n0 + n1) {
        const float* w2; const float* b2; _Float16* BF; int IN, rel;
        if (idx < n0) { w2 = w2_0; b2 = b2_0; BF = BF0; IN = 32; rel = idx; }
        else          { w2 = w2_1; b2 = b2_1; BF = BF1; IN = 64; rel = idx - n0; }
        int j = rel & 7, lane = (rel >> 3) & 63, f = rel >> 9;
        int nf = f & 1, kk16 = f >> 1;
        int ln = lane & 31, g2 = lane >> 5;
        int k = kk16 * 16 + g2 * 8 + j;
        int ko = k / IN, i = k - ko * IN;
        int o = nf * 32 + ln;
        float v = (ko < 64) ? w2[ko * (IN * 64) + i * 64 + o]
                : (ko == 64 ? b2[i * 64 + o] : 0.f);
        BF[rel] = (_Float16)v;
        return;
    }
    idx -= (n0 + n1);
    if (idx >= N * 64) return;
    int n = idx >> 6, o = idx & 63;
    float s = bias[o];
    const float* xr = x + (size_t)n * 32;
    #pragma unroll 8
    for (int i = 0; i < 32; ++i) s += xr[i] * root[i * 64 + o];
    agg[idx] = s;
    if (o < 32) xb[n * 32 + o] = (_Float16)xr[o];
}

// x1b = f16(relu(agg0)); agg1[n,o] = bias1[o] + sum_i relu(agg0[n,i])*root1[i,o]
__global__ void mid_kernel(const float* __restrict__ agg0, const float* __restrict__ root1,
                           const float* __restrict__ bias1, _Float16* __restrict__ x1b,
                           float* __restrict__ agg1, int N) {
    int idx = blockIdx.x * 256 + threadIdx.x;
    if (idx >= N * 64) return;
    int n = idx >> 6, o = idx & 63;
    const float* ar = agg0 + (size_t)n * 64;
    float s = bias1[o];
    #pragma unroll 8
    for (int i = 0; i < 64; ++i) s += fmaxf(ar[i], 0.f) * root1[i * 64 + o];
    agg1[idx] = s;
    x1b[idx] = (_Float16)fmaxf(agg0[idx], 0.f);
}

__global__ void final_relu(const float* __restrict__ agg1, float* __restrict__ out, int n) {
    int idx = blockIdx.x * 256 + threadIdx.x;
    if (idx < n) out[idx] = fmaxf(agg1[idx], 0.f);
}

// ---------------------------------------------------------------------------
// Edge GEMM v9: 256-edge tile, 512 threads = 8 waves -> 2 waves per SIMD
// CO-RESIDENT BY CONSTRUCTION (rocprof showed the inter-block scheduler keeps
// only 1 workgroup/CU: occupancy pinned at ~11% = 1 wave/SIMD across v6-v8,
// which serializes loads/VALU/MFMA on each SIMD and capped MfmaUtil at ~24%).
// Wave w = (nf = w&1, kh = (w>>1)&1, mh = w>>2): nf = 32-col half,
// kh = K-half, mh = which 128-edge half. Each wave: 4 m-slices, 4 acc,
// v7's proven double-buffered L2->reg B stream (no barrier in K-loop).
// Grid = ceil(E/256) = 196 blocks <= 256 CUs -> single-round schedule.
// K-half combine buffer overlays sh_x/sh_r1 (dead after K-loop). One global
// atomic per output element.
// ---------------------------------------------------------------------------
template<int IN_C>
__global__ __launch_bounds__(512, 2)
void edge_gemm(const float* __restrict__ ea,
               const float* __restrict__ w1, const float* __restrict__ b1,
               const _Float16* __restrict__ xb, const _Float16* __restrict__ BF,
               const int* __restrict__ srcI, const int* __restrict__ dstI,
               float* __restrict__ agg, int E) {
    constexpr int PH  = IN_C / 16;        // fragments per ko per nf
    constexpr int CPR = IN_C / 8;         // 16B chunks per x row
    constexpr int M   = 256;              // edges per block

    constexpr size_t XBYTES = (size_t)M * IN_C * 2;     // sh_x
    constexpr size_t RBYTES = (size_t)M * 66 * 2;       // sh_r1
    constexpr size_t BBYTES = (size_t)M * 65 * 4;       // reduction buf
    constexpr size_t SBYTES = (XBYTES + RBYTES > BBYTES) ? (XBYTES + RBYTES) : BBYTES;

    __shared__ __align__(16) char smem[SBYTES];
    __shared__ int sh_dst[M];
    auto sh_x  = (_Float16 (*)[IN_C])smem;              // live: prologue..K-loop
    auto sh_r1 = (_Float16 (*)[66])(smem + XBYTES);     // live: prologue..K-loop
    auto buf   = (float (*)[65])smem;                   // live: after 2nd barrier

    int tid = threadIdx.x;
    int ebase = blockIdx.x * M;
    int valid = E - ebase; if (valid > M) valid = M;

    if (tid < M) {
        sh_dst[tid] = (tid < valid) ? dstI[ebase + tid] : 0;
        sh_r1[tid][64] = (_Float16)1.f;   // scale 1 for the b2 row of BF
        sh_r1[tid][65] = (_Float16)0.f;   // scale 0 for the zero-pad row
    }
    // r1 tile computed in-kernel: relu(ea @ w1 + b1)
    for (int i = tid; i < M * 64; i += 512) {
        int e = i >> 6, j = i & 63;
        int ge = (e < valid) ? (ebase + e) : ebase;
        float2 av = *(const float2*)(ea + (size_t)ge * 2);
        sh_r1[e][j] = (_Float16)fmaxf(av.x * w1[j] + av.y * w1[64 + j] + b1[j], 0.f);
    }
    // gathered x tile
    for (int i = tid; i < M * CPR; i += 512) {
        int r = i / CPR, c = i - r * CPR;
        int sidx = (r < valid) ? srcI[ebase + r] : 0;
        *(uint4*)&sh_x[r][c * 8] = *(const uint4*)(xb + (size_t)sidx * IN_C + (size_t)c * 8);
    }
    __syncthreads();

    int wv = tid >> 6, lane = tid & 63, ln = lane & 31, g2 = lane >> 5;
    int nf = wv & 1, kh = (wv >> 1) & 1, mh = wv >> 2;
    int mbase = mh * 128;

    // x slices for the wave's four m-slices (rows mbase + s*32 + ln)
    v8h xs0[PH], xs1[PH], xs2[PH], xs3[PH];
    #pragma unroll
    for (int p = 0; p < PH; ++p) {
        xs0[p] = *(const v8h*)&sh_x[mbase + ln     ][p * 16 + g2 * 8];
        xs1[p] = *(const v8h*)&sh_x[mbase + ln + 32][p * 16 + g2 * 8];
        xs2[p] = *(const v8h*)&sh_x[mbase + ln + 64][p * 16 + g2 * 8];
        xs3[p] = *(const v8h*)&sh_x[mbase + ln + 96][p * 16 + g2 * 8];
    }

    v16f acc0 = {0,0,0,0,0,0,0,0,0,0,0,0,0,0,0,0};
    v16f acc1 = acc0, acc2 = acc0, acc3 = acc0;

    // wave's fragment stream: frag(ko,p) at uint4 index (ko*PH+p)*128 + nf*64 + lane
    const uint4* bp = (const uint4*)BF + (size_t)nf * 64 + lane;
    int kb = kh * 33;                     // 33 ko per K-half (66 total incl bias+pad)

    uint4 b[PH], bn[PH];
    auto LD = [&](uint4 (&d)[PH], int ko) {
        #pragma unroll
        for (int p = 0; p < PH; ++p) d[p] = bp[(size_t)(ko * PH + p) * 128];
    };
    auto FM = [&](uint4 (&d)[PH], int ko) {
        _Float16 sv0 = sh_r1[mbase + ln     ][ko];
        _Float16 sv1 = sh_r1[mbase + ln + 32][ko];
        _Float16 sv2 = sh_r1[mbase + ln + 64][ko];
        _Float16 sv3 = sh_r1[mbase + ln + 96][ko];
        #pragma unroll
        for (int p = 0; p < PH; ++p) {
            v8h bb; __builtin_memcpy(&bb, &d[p], 16);
            acc0 = __builtin_amdgcn_mfma_f32_32x32x16_f16(xs0[p] * sv0, bb, acc0, 0, 0, 0);
            acc1 = __builtin_amdgcn_mfma_f32_32x32x16_f16(xs1[p] * sv1, bb, acc1, 0, 0, 0);
            acc2 = __builtin_amdgcn_mfma_f32_32x32x16_f16(xs2[p] * sv2, bb, acc2, 0, 0, 0);
            acc3 = __builtin_amdgcn_mfma_f32_32x32x16_f16(xs3[p] * sv3, bb, acc3, 0, 0, 0);
        }
    };

    LD(b, kb);
    #pragma unroll 1
    for (int t = 0; t < 16; ++t) {        // ko pairs; b/bn double buffer
        LD(bn, kb + 2 * t + 1);
        FM(b,  kb + 2 * t);
        LD(b,  kb + 2 * t + 2);           // max ko touched = kb+32 (<=65)
        FM(bn, kb + 2 * t + 1);
    }
    FM(b, kb + 32);                       // 33rd ko

    // ---- combine K-halves. buf overlays sh_x/sh_r1: barrier first so every
    // wave is done reading them, then kh=1 stores, barrier, kh=0 adds+atomics.
    int colb = nf * 32 + ln;
    __syncthreads();
    if (kh == 1) {
        #pragma unroll
        for (int r = 0; r < 16; ++r) {
            int row = mbase + 4 * g2 + (r & 3) + 8 * (r >> 2);
            buf[row     ][colb] = acc0[r];
            buf[row + 32][colb] = acc1[r];
            buf[row + 64][colb] = acc2[r];
            buf[row + 96][colb] = acc3[r];
        }
    }
    __syncthreads();
    if (kh == 0) {
        #pragma unroll
        for (int r = 0; r < 16; ++r) {
            int row = mbase + 4 * g2 + (r & 3) + 8 * (r >> 2);
            if (row < valid)
                atomicAdd(&agg[(size_t)sh_dst[row] * 64 + colb], acc0[r] + buf[row][colb]);
            int row1 = row + 32;
            if (row1 < valid)
                atomicAdd(&agg[(size_t)sh_dst[row1] * 64 + colb], acc1[r] + buf[row1][colb]);
            int row2 = row + 64;
            if (row2 < valid)
                atomicAdd(&agg[(size_t)sh_dst[row2] * 64 + colb], acc2[r] + buf[row2][colb]);
            int row3 = row + 96;
            if (row3 < valid)
                atomicAdd(&agg[(size_t)sh_dst[row3] * 64 + colb], acc3[r] + buf[row3][colb]);
        }
    }
}

// ---------------------------------------------------------------------------
extern "C" void kernel_launch(void* const* d_in, const int* in_sizes, int n_in,
                              void* d_out, int out_size, void* d_ws, size_t ws_size,
                              hipStream_t stream) {
    const float* x      = (const float*)d_in[0];
    const int*   ei     = (const int*)d_in[1];
    const float* ea     = (const float*)d_in[2];
    const float* w1_0   = (const float*)d_in[3];
    const float* b1_0   = (const float*)d_in[4];
    const float* w2_0   = (const float*)d_in[5];
    const float* b2_0   = (const float*)d_in[6];
    const float* root_0 = (const float*)d_in[7];
    const float* bias_0 = (const float*)d_in[8];
    const float* w1_1   = (const float*)d_in[9];
    const float* b1_1   = (const float*)d_in[10];
    const float* w2_1   = (const float*)d_in[11];
    const float* b2_1   = (const float*)d_in[12];
    const float* root_1 = (const float*)d_in[13];
    const float* bias_1 = (const float*)d_in[14];
    float* out = (float*)d_out;

    int N = in_sizes[0] / 32;
    int E = in_sizes[1] / 2;
    const int* srcI = ei;
    const int* dstI = ei + E;

    char* ws = (char*)d_ws;
    size_t off = 0;
    auto carve = [&](size_t bytes) {
        void* p = ws + off;
        off += (bytes + 255) & ~(size_t)255;
        return p;
    };
    _Float16* BF0  = (_Float16*)carve((size_t)264 * 512 * 2);
    _Float16* BF1  = (_Float16*)carve((size_t)528 * 512 * 2);
    _Float16* XB0  = (_Float16*)carve((size_t)N * 32 * 2);
    _Float16* X1B  = (_Float16*)carve((size_t)N * 64 * 2);
    float*    AGG0 = (float*)carve((size_t)N * 64 * 4);
    float*    AGG1 = (float*)carve((size_t)N * 64 * 4);

    int tprep = (264 + 528) * 512 + N * 64;
    prep_fused<<<(tprep + 255) / 256, 256, 0, stream>>>(w2_0, b2_0, BF0, w2_1, b2_1, BF1,
                                                        x, root_0, bias_0, AGG0, XB0, N);

    int gblocks = (E + 255) / 256;
    edge_gemm<32><<<gblocks, 512, 0, stream>>>(ea, w1_0, b1_0, XB0, BF0, srcI, dstI, AGG0, E);

    mid_kernel<<<(N * 64 + 255) / 256, 256, 0, stream>>>(AGG0, root_1, bias_1, X1B, AGG1, N);

    edge_gemm<64><<<gblocks, 512, 0, stream>>>(ea, w1_1, b1_1, X1B, BF1, srcI, dstI, AGG1, E);

    final_relu<<<(N * 64 + 255) / 256, 256, 0, stream>>>(AGG1, out, N * 64);
}

// Round 5
// 192.884 us; speedup vs baseline: 1.0296x; 1.0015x over previous
//
#include <hip/hip_runtime.h>

typedef _Float16 v8h __attribute__((ext_vector_type(8)));
typedef float v16f __attribute__((ext_vector_type(16)));

// ---------------------------------------------------------------------------
// BF: B in MFMA-fragment order, padded to 66 ko (pad rows = 0).
// Fragment f = kk16*2 + nf holds at [lane*8 + j]:
//   B[k = kk16*16 + (lane>>5)*8 + j][o = nf*32 + (lane&31)]
// where B[k][o] = (ko<64) ? w2[ko, i*64+o] : (ko==64 ? b2[i*64+o] : 0),
// ko = k/IN, i = k%IN. kk16 = ko*PH + p.
//
// prep_fused also computes agg0 = bias0 + x@root0 and emits x in f16.
// ---------------------------------------------------------------------------
__global__ void prep_fused(const float* __restrict__ w2_0, const float* __restrict__ b2_0,
                           _Float16* __restrict__ BF0,
                           const float* __restrict__ w2_1, const float* __restrict__ b2_1,
                           _Float16* __restrict__ BF1,
                           const float* __restrict__ x, const float* __restrict__ root,
                           const float* __restrict__ bias, float* __restrict__ agg,
                           _Float16* __restrict__ xb, int N) {
    int idx = blockIdx.x * 256 + threadIdx.x;
    const int n0 = 264 * 512;   // layer0: 66 ko * 2 kk16/ko * 2 nf
    const int n1 = 528 * 512;   // layer1: 66 ko * 4 kk16/ko * 2 nf
    if (idx < n0 + n1) {
        const float* w2; const float* b2; _Float16* BF; int IN, rel;
        if (idx < n0) { w2 = w2_0; b2 = b2_0; BF = BF0; IN = 32; rel = idx; }
        else          { w2 = w2_1; b2 = b2_1; BF = BF1; IN = 64; rel = idx - n0; }
        int j = rel & 7, lane = (rel >> 3) & 63, f = rel >> 9;
        int nf = f & 1, kk16 = f >> 1;
        int ln = lane & 31, g2 = lane >> 5;
        int k = kk16 * 16 + g2 * 8 + j;
        int ko = k / IN, i = k - ko * IN;
        int o = nf * 32 + ln;
        float v = (ko < 64) ? w2[ko * (IN * 64) + i * 64 + o]
                : (ko == 64 ? b2[i * 64 + o] : 0.f);
        BF[rel] = (_Float16)v;
        return;
    }
    idx -= (n0 + n1);
    if (idx >= N * 64) return;
    int n = idx >> 6, o = idx & 63;
    float s = bias[o];
    const float* xr = x + (size_t)n * 32;
    #pragma unroll 8
    for (int i = 0; i < 32; ++i) s += xr[i] * root[i * 64 + o];
    agg[idx] = s;
    if (o < 32) xb[n * 32 + o] = (_Float16)xr[o];
}

// x1b = f16(relu(agg0)); agg1[n,o] = bias1[o] + sum_i relu(agg0[n,i])*root1[i,o]
__global__ void mid_kernel(const float* __restrict__ agg0, const float* __restrict__ root1,
                           const float* __restrict__ bias1, _Float16* __restrict__ x1b,
                           float* __restrict__ agg1, int N) {
    int idx = blockIdx.x * 256 + threadIdx.x;
    if (idx >= N * 64) return;
    int n = idx >> 6, o = idx & 63;
    const float* ar = agg0 + (size_t)n * 64;
    float s = bias1[o];
    #pragma unroll 8
    for (int i = 0; i < 64; ++i) s += fmaxf(ar[i], 0.f) * root1[i * 64 + o];
    agg1[idx] = s;
    x1b[idx] = (_Float16)fmaxf(agg0[idx], 0.f);
}

__global__ void final_relu(const float* __restrict__ agg1, float* __restrict__ out, int n) {
    int idx = blockIdx.x * 256 + threadIdx.x;
    if (idx < n) out[idx] = fmaxf(agg1[idx], 0.f);
}

// ---------------------------------------------------------------------------
// Edge GEMM v10: v9 structure (256-edge tile, 512 threads = 8 waves = 2
// waves/SIMD co-resident by construction) with __launch_bounds__(512, 1).
// v9's (512,2) forced a 128-VGPR/wave budget: VGPR_Count dropped to 88 and
// the compiler EVICTED the xs fragments (need 64 VGPRs) from registers,
// rematerializing them from LDS inside every FM -> ~16 extra ds_read_b64
// (~120 cyc latency) per ko on the K-loop critical path. (512,1) restores
// the 256-VGPR budget (~160 needed, same inner loop as v7's 96+64agpr) while
// m69's occupancy rule still gives 2 waves/SIMD at <=256 VGPR.
// Wave w = (nf = w&1, kh = (w>>1)&1, mh = w>>2). Each wave: 4 m-slices,
// 4 acc, double-buffered L2->reg B stream, no barrier in K-loop.
// Grid = ceil(E/256) = 196 blocks <= 256 CUs -> single-round schedule.
// K-half combine buffer overlays sh_x/sh_r1 (dead after K-loop). One global
// atomic per output element.
// ---------------------------------------------------------------------------
template<int IN_C>
__global__ __launch_bounds__(512, 1)
void edge_gemm(const float* __restrict__ ea,
               const float* __restrict__ w1, const float* __restrict__ b1,
               const _Float16* __restrict__ xb, const _Float16* __restrict__ BF,
               const int* __restrict__ srcI, const int* __restrict__ dstI,
               float* __restrict__ agg, int E) {
    constexpr int PH  = IN_C / 16;        // fragments per ko per nf
    constexpr int CPR = IN_C / 8;         // 16B chunks per x row
    constexpr int M   = 256;              // edges per block

    constexpr size_t XBYTES = (size_t)M * IN_C * 2;     // sh_x
    constexpr size_t RBYTES = (size_t)M * 66 * 2;       // sh_r1
    constexpr size_t BBYTES = (size_t)M * 65 * 4;       // reduction buf
    constexpr size_t SBYTES = (XBYTES + RBYTES > BBYTES) ? (XBYTES + RBYTES) : BBYTES;

    __shared__ __align__(16) char smem[SBYTES];
    __shared__ int sh_dst[M];
    auto sh_x  = (_Float16 (*)[IN_C])smem;              // live: prologue..K-loop
    auto sh_r1 = (_Float16 (*)[66])(smem + XBYTES);     // live: prologue..K-loop
    auto buf   = (float (*)[65])smem;                   // live: after 2nd barrier

    int tid = threadIdx.x;
    int ebase = blockIdx.x * M;
    int valid = E - ebase; if (valid > M) valid = M;

    if (tid < M) {
        sh_dst[tid] = (tid < valid) ? dstI[ebase + tid] : 0;
        sh_r1[tid][64] = (_Float16)1.f;   // scale 1 for the b2 row of BF
        sh_r1[tid][65] = (_Float16)0.f;   // scale 0 for the zero-pad row
    }
    // r1 tile computed in-kernel: relu(ea @ w1 + b1)
    for (int i = tid; i < M * 64; i += 512) {
        int e = i >> 6, j = i & 63;
        int ge = (e < valid) ? (ebase + e) : ebase;
        float2 av = *(const float2*)(ea + (size_t)ge * 2);
        sh_r1[e][j] = (_Float16)fmaxf(av.x * w1[j] + av.y * w1[64 + j] + b1[j], 0.f);
    }
    // gathered x tile
    for (int i = tid; i < M * CPR; i += 512) {
        int r = i / CPR, c = i - r * CPR;
        int sidx = (r < valid) ? srcI[ebase + r] : 0;
        *(uint4*)&sh_x[r][c * 8] = *(const uint4*)(xb + (size_t)sidx * IN_C + (size_t)c * 8);
    }
    __syncthreads();

    int wv = tid >> 6, lane = tid & 63, ln = lane & 31, g2 = lane >> 5;
    int nf = wv & 1, kh = (wv >> 1) & 1, mh = wv >> 2;
    int mbase = mh * 128;

    // x slices for the wave's four m-slices (rows mbase + s*32 + ln)
    v8h xs0[PH], xs1[PH], xs2[PH], xs3[PH];
    #pragma unroll
    for (int p = 0; p < PH; ++p) {
        xs0[p] = *(const v8h*)&sh_x[mbase + ln     ][p * 16 + g2 * 8];
        xs1[p] = *(const v8h*)&sh_x[mbase + ln + 32][p * 16 + g2 * 8];
        xs2[p] = *(const v8h*)&sh_x[mbase + ln + 64][p * 16 + g2 * 8];
        xs3[p] = *(const v8h*)&sh_x[mbase + ln + 96][p * 16 + g2 * 8];
    }

    v16f acc0 = {0,0,0,0,0,0,0,0,0,0,0,0,0,0,0,0};
    v16f acc1 = acc0, acc2 = acc0, acc3 = acc0;

    // wave's fragment stream: frag(ko,p) at uint4 index (ko*PH+p)*128 + nf*64 + lane
    const uint4* bp = (const uint4*)BF + (size_t)nf * 64 + lane;
    int kb = kh * 33;                     // 33 ko per K-half (66 total incl bias+pad)

    uint4 b[PH], bn[PH];
    auto LD = [&](uint4 (&d)[PH], int ko) {
        #pragma unroll
        for (int p = 0; p < PH; ++p) d[p] = bp[(size_t)(ko * PH + p) * 128];
    };
    auto FM = [&](uint4 (&d)[PH], int ko) {
        _Float16 sv0 = sh_r1[mbase + ln     ][ko];
        _Float16 sv1 = sh_r1[mbase + ln + 32][ko];
        _Float16 sv2 = sh_r1[mbase + ln + 64][ko];
        _Float16 sv3 = sh_r1[mbase + ln + 96][ko];
        #pragma unroll
        for (int p = 0; p < PH; ++p) {
            v8h bb; __builtin_memcpy(&bb, &d[p], 16);
            acc0 = __builtin_amdgcn_mfma_f32_32x32x16_f16(xs0[p] * sv0, bb, acc0, 0, 0, 0);
            acc1 = __builtin_amdgcn_mfma_f32_32x32x16_f16(xs1[p] * sv1, bb, acc1, 0, 0, 0);
            acc2 = __builtin_amdgcn_mfma_f32_32x32x16_f16(xs2[p] * sv2, bb, acc2, 0, 0, 0);
            acc3 = __builtin_amdgcn_mfma_f32_32x32x16_f16(xs3[p] * sv3, bb, acc3, 0, 0, 0);
        }
    };

    LD(b, kb);
    #pragma unroll 1
    for (int t = 0; t < 16; ++t) {        // ko pairs; b/bn double buffer
        LD(bn, kb + 2 * t + 1);
        FM(b,  kb + 2 * t);
        LD(b,  kb + 2 * t + 2);           // max ko touched = kb+32 (<=65)
        FM(bn, kb + 2 * t + 1);
    }
    FM(b, kb + 32);                       // 33rd ko

    // ---- combine K-halves. buf overlays sh_x/sh_r1: barrier first so every
    // wave is done reading them, then kh=1 stores, barrier, kh=0 adds+atomics.
    int colb = nf * 32 + ln;
    __syncthreads();
    if (kh == 1) {
        #pragma unroll
        for (int r = 0; r < 16; ++r) {
            int row = mbase + 4 * g2 + (r & 3) + 8 * (r >> 2);
            buf[row     ][colb] = acc0[r];
            buf[row + 32][colb] = acc1[r];
            buf[row + 64][colb] = acc2[r];
            buf[row + 96][colb] = acc3[r];
        }
    }
    __syncthreads();
    if (kh == 0) {
        #pragma unroll
        for (int r = 0; r < 16; ++r) {
            int row = mbase + 4 * g2 + (r & 3) + 8 * (r >> 2);
            if (row < valid)
                atomicAdd(&agg[(size_t)sh_dst[row] * 64 + colb], acc0[r] + buf[row][colb]);
            int row1 = row + 32;
            if (row1 < valid)
                atomicAdd(&agg[(size_t)sh_dst[row1] * 64 + colb], acc1[r] + buf[row1][colb]);
            int row2 = row + 64;
            if (row2 < valid)
                atomicAdd(&agg[(size_t)sh_dst[row2] * 64 + colb], acc2[r] + buf[row2][colb]);
            int row3 = row + 96;
            if (row3 < valid)
                atomicAdd(&agg[(size_t)sh_dst[row3] * 64 + colb], acc3[r] + buf[row3][colb]);
        }
    }
}

// ---------------------------------------------------------------------------
extern "C" void kernel_launch(void* const* d_in, const int* in_sizes, int n_in,
                              void* d_out, int out_size, void* d_ws, size_t ws_size,
                              hipStream_t stream) {
    const float* x      = (const float*)d_in[0];
    const int*   ei     = (const int*)d_in[1];
    const float* ea     = (const float*)d_in[2];
    const float* w1_0   = (const float*)d_in[3];
    const float* b1_0   = (const float*)d_in[4];
    const float* w2_0   = (const float*)d_in[5];
    const float* b2_0   = (const float*)d_in[6];
    const float* root_0 = (const float*)d_in[7];
    const float* bias_0 = (const float*)d_in[8];
    const float* w1_1   = (const float*)d_in[9];
    const float* b1_1   = (const float*)d_in[10];
    const float* w2_1   = (const float*)d_in[11];
    const float* b2_1   = (const float*)d_in[12];
    const float* root_1 = (const float*)d_in[13];
    const float* bias_1 = (const float*)d_in[14];
    float* out = (float*)d_out;

    int N = in_sizes[0] / 32;
    int E = in_sizes[1] / 2;
    const int* srcI = ei;
    const int* dstI = ei + E;

    char* ws = (char*)d_ws;
    size_t off = 0;
    auto carve = [&](size_t bytes) {
        void* p = ws + off;
        off += (bytes + 255) & ~(size_t)255;
        return p;
    };
    _Float16* BF0  = (_Float16*)carve((size_t)264 * 512 * 2);
    _Float16* BF1  = (_Float16*)carve((size_t)528 * 512 * 2);
    _Float16* XB0  = (_Float16*)carve((size_t)N * 32 * 2);
    _Float16* X1B  = (_Float16*)carve((size_t)N * 64 * 2);
    float*    AGG0 = (float*)carve((size_t)N * 64 * 4);
    float*    AGG1 = (float*)carve((size_t)N * 64 * 4);

    int tprep = (264 + 528) * 512 + N * 64;
    prep_fused<<<(tprep + 255) / 256, 256, 0, stream>>>(w2_0, b2_0, BF0, w2_1, b2_1, BF1,
                                                        x, root_0, bias_0, AGG0, XB0, N);

    int gblocks = (E + 255) / 256;
    edge_gemm<32><<<gblocks, 512, 0, stream>>>(ea, w1_0, b1_0, XB0, BF0, srcI, dstI, AGG0, E);

    mid_kernel<<<(N * 64 + 255) / 256, 256, 0, stream>>>(AGG0, root_1, bias_1, X1B, AGG1, N);

    edge_gemm<64><<<gblocks, 512, 0, stream>>>(ea, w1_1, b1_1, X1B, BF1, srcI, dstI, AGG1, E);

    final_relu<<<(N * 64 + 255) / 256, 256, 0, stream>>>(AGG1, out, N * 64);
}

// Round 6
// 190.851 us; speedup vs baseline: 1.0406x; 1.0106x over previous
//
#include <hip/hip_runtime.h>

typedef _Float16 v8h __attribute__((ext_vector_type(8)));
typedef float v16f __attribute__((ext_vector_type(16)));

// ---------------------------------------------------------------------------
// BF: B in MFMA-fragment order, padded to 66 ko (pad rows = 0).
// Fragment f = kk16*2 + nf holds at [lane*8 + j]:
//   B[k = kk16*16 + (lane>>5)*8 + j][o = nf*32 + (lane&31)]
// where B[k][o] = (ko<64) ? w2[ko, i*64+o] : (ko==64 ? b2[i*64+o] : 0),
// ko = k/IN, i = k%IN. kk16 = ko*PH + p.  (row 65 pad is no longer read.)
//
// prep_fused also computes agg0 = bias0 + x@root0 and emits x in f16.
// ---------------------------------------------------------------------------
__global__ void prep_fused(const float* __restrict__ w2_0, const float* __restrict__ b2_0,
                           _Float16* __restrict__ BF0,
                           const float* __restrict__ w2_1, const float* __restrict__ b2_1,
                           _Float16* __restrict__ BF1,
                           const float* __restrict__ x, const float* __restrict__ root,
                           const float* __restrict__ bias, float* __restrict__ agg,
                           _Float16* __restrict__ xb, int N) {
    int idx = blockIdx.x * 256 + threadIdx.x;
    const int n0 = 264 * 512;   // layer0: 66 ko * 2 kk16/ko * 2 nf
    const int n1 = 528 * 512;   // layer1: 66 ko * 4 kk16/ko * 2 nf
    if (idx < n0 + n1) {
        const float* w2; const float* b2; _Float16* BF; int IN, rel;
        if (idx < n0) { w2 = w2_0; b2 = b2_0; BF = BF0; IN = 32; rel = idx; }
        else          { w2 = w2_1; b2 = b2_1; BF = BF1; IN = 64; rel = idx - n0; }
        int j = rel & 7, lane = (rel >> 3) & 63, f = rel >> 9;
        int nf = f & 1, kk16 = f >> 1;
        int ln = lane & 31, g2 = lane >> 5;
        int k = kk16 * 16 + g2 * 8 + j;
        int ko = k / IN, i = k - ko * IN;
        int o = nf * 32 + ln;
        float v = (ko < 64) ? w2[ko * (IN * 64) + i * 64 + o]
                : (ko == 64 ? b2[i * 64 + o] : 0.f);
        BF[rel] = (_Float16)v;
        return;
    }
    idx -= (n0 + n1);
    if (idx >= N * 64) return;
    int n = idx >> 6, o = idx & 63;
    float s = bias[o];
    const float* xr = x + (size_t)n * 32;
    #pragma unroll 8
    for (int i = 0; i < 32; ++i) s += xr[i] * root[i * 64 + o];
    agg[idx] = s;
    if (o < 32) xb[n * 32 + o] = (_Float16)xr[o];
}

// x1b = f16(relu(agg0)); agg1[n,o] = bias1[o] + sum_i relu(agg0[n,i])*root1[i,o]
__global__ void mid_kernel(const float* __restrict__ agg0, const float* __restrict__ root1,
                           const float* __restrict__ bias1, _Float16* __restrict__ x1b,
                           float* __restrict__ agg1, int N) {
    int idx = blockIdx.x * 256 + threadIdx.x;
    if (idx >= N * 64) return;
    int n = idx >> 6, o = idx & 63;
    const float* ar = agg0 + (size_t)n * 64;
    float s = bias1[o];
    #pragma unroll 8
    for (int i = 0; i < 64; ++i) s += fmaxf(ar[i], 0.f) * root1[i * 64 + o];
    agg1[idx] = s;
    x1b[idx] = (_Float16)fmaxf(agg0[idx], 0.f);
}

__global__ void final_relu(const float* __restrict__ agg1, float* __restrict__ out, int n) {
    int idx = blockIdx.x * 256 + threadIdx.x;
    if (idx < n) out[idx] = fmaxf(agg1[idx], 0.f);
}

// ---------------------------------------------------------------------------
// Edge GEMM v11: 256-edge tile, 512 threads = 8 waves (2 waves/SIMD
// co-resident by construction). Wave w = (nf = w&1, q = w>>1): nf = 32-col
// half, q = which 64-edge quarter; each wave owns the FULL K range (65 ko).
// Rationale from v6-v10 counters: v7's 2-slice wave shape is the only one
// the compiler keeps fully register-resident (96 VGPR; 3-4-slice variants
// dropped to 88-116 and rematerialized xs from LDS every FM through a
// 32-way-conflicted 128B-stride layout -> constant ~700K bank-conflict
// cycles and MfmaUtil pinned at ~20-24%). v11 = v7's register shape x 2
// waves/SIMD, so the per-FM latency chain (sv ds_read ~120cyc, B vmcnt
// ~200cyc L2) overlaps across co-resident waves.
// Full-K waves also DELETE the kh-combine phase entirely: no LDS buf, no
// barriers after the K-loop, each wave atomicAdds its finished outputs
// (still exactly one atomic per output element).
// sh_x is stored PRE-SWIZZLED in MFMA-fragment order so fragment reads are
// the canonical contiguous 16B/lane pattern (no same-bank column reads).
// Grid = ceil(E/256) = 196 blocks <= 256 CUs -> single-round schedule.
// ---------------------------------------------------------------------------
template<int IN_C>
__global__ __launch_bounds__(512, 1)
void edge_gemm(const float* __restrict__ ea,
               const float* __restrict__ w1, const float* __restrict__ b1,
               const _Float16* __restrict__ xb, const _Float16* __restrict__ BF,
               const int* __restrict__ srcI, const int* __restrict__ dstI,
               float* __restrict__ agg, int E) {
    constexpr int PH  = IN_C / 16;        // fragments per ko per nf
    constexpr int CPR = IN_C / 8;         // 16B chunks per x row
    constexpr int M   = 256;              // edges per block
    constexpr int NCH = M * CPR;          // total 16B chunks in x tile

    // x tile in fragment order: uint4 index ((s*PH + p)*2 + g2)*32 + ln
    // holds x[edge = s*32 + ln][k = p*16 + g2*8 .. +8)
    __shared__ __align__(16) uint4 sh_xf[NCH];
    __shared__ _Float16 sh_r1[M][66];
    __shared__ int sh_dst[M];

    int tid = threadIdx.x;
    int ebase = blockIdx.x * M;
    int valid = E - ebase; if (valid > M) valid = M;

    if (tid < M) {
        sh_dst[tid] = (tid < valid) ? dstI[ebase + tid] : 0;
        sh_r1[tid][64] = (_Float16)1.f;   // scale 1 for the b2 row of BF
    }
    // r1 tile computed in-kernel: relu(ea @ w1 + b1)
    for (int i = tid; i < M * 64; i += 512) {
        int e = i >> 6, j = i & 63;
        int ge = (e < valid) ? (ebase + e) : ebase;
        float2 av = *(const float2*)(ea + (size_t)ge * 2);
        sh_r1[e][j] = (_Float16)fmaxf(av.x * w1[j] + av.y * w1[64 + j] + b1[j], 0.f);
    }
    // gathered x tile, written in DEST (fragment) order so LDS writes are
    // lane-contiguous: dest d -> ln = d&31, g2 = (d>>5)&1, p = (d>>6)%PH,
    // s = (d>>6)/PH; source row r = s*32+ln, chunk c = p*2+g2.
    for (int d = tid; d < NCH; d += 512) {
        int ln = d & 31, g2 = (d >> 5) & 1;
        int sp = d >> 6;
        int p = sp & (PH - 1), s = sp / PH;
        int r = s * 32 + ln;
        int c = p * 2 + g2;
        int sidx = (r < valid) ? srcI[ebase + r] : 0;
        sh_xf[d] = *(const uint4*)(xb + (size_t)sidx * IN_C + (size_t)c * 8);
    }
    __syncthreads();

    int wv = tid >> 6, lane = tid & 63, ln = lane & 31, g2 = lane >> 5;
    int nf = wv & 1, q = wv >> 1;
    int sg0 = q * 2, sg1 = q * 2 + 1;     // the wave's two 32-edge slices

    // x slices (2 slices x PH fragments = 32 VGPR -> stays resident, v7-proven)
    v8h xs0[PH], xs1[PH];
    #pragma unroll
    for (int p = 0; p < PH; ++p) {
        xs0[p] = *(const v8h*)&sh_xf[((sg0 * PH + p) * 2 + g2) * 32 + ln];
        xs1[p] = *(const v8h*)&sh_xf[((sg1 * PH + p) * 2 + g2) * 32 + ln];
    }

    v16f acc0 = {0,0,0,0,0,0,0,0,0,0,0,0,0,0,0,0};
    v16f acc1 = acc0;

    // wave's fragment stream: frag(ko,p) at uint4 index (ko*PH+p)*128 + nf*64 + lane
    const uint4* bp = (const uint4*)BF + (size_t)nf * 64 + lane;

    uint4 b[PH], bn[PH];
    auto LD = [&](uint4 (&d)[PH], int ko) {
        #pragma unroll
        for (int p = 0; p < PH; ++p) d[p] = bp[(size_t)(ko * PH + p) * 128];
    };
    auto FM = [&](uint4 (&d)[PH], int ko) {
        _Float16 sv0 = sh_r1[sg0 * 32 + ln][ko];
        _Float16 sv1 = sh_r1[sg1 * 32 + ln][ko];
        #pragma unroll
        for (int p = 0; p < PH; ++p) {
            v8h bb; __builtin_memcpy(&bb, &d[p], 16);
            acc0 = __builtin_amdgcn_mfma_f32_32x32x16_f16(xs0[p] * sv0, bb, acc0, 0, 0, 0);
            acc1 = __builtin_amdgcn_mfma_f32_32x32x16_f16(xs1[p] * sv1, bb, acc1, 0, 0, 0);
        }
    };

    // full K: ko = 0..64 (64 w2 rows + bias row), b/bn double buffer
    LD(b, 0);
    #pragma unroll 1
    for (int t = 0; t < 32; ++t) {
        LD(bn, 2 * t + 1);
        FM(b,  2 * t);
        LD(b,  2 * t + 2);                // max ko touched = 64 (<=65)
        FM(bn, 2 * t + 1);
    }
    FM(b, 64);                            // 65th ko (bias row)

    // direct epilogue: one atomic per output element, no combine phase
    int colb = nf * 32 + ln;
    #pragma unroll
    for (int r = 0; r < 16; ++r) {
        int row = q * 64 + 4 * g2 + (r & 3) + 8 * (r >> 2);
        if (row < valid)
            atomicAdd(&agg[(size_t)sh_dst[row] * 64 + colb], acc0[r]);
        int row1 = row + 32;
        if (row1 < valid)
            atomicAdd(&agg[(size_t)sh_dst[row1] * 64 + colb], acc1[r]);
    }
}

// ---------------------------------------------------------------------------
extern "C" void kernel_launch(void* const* d_in, const int* in_sizes, int n_in,
                              void* d_out, int out_size, void* d_ws, size_t ws_size,
                              hipStream_t stream) {
    const float* x      = (const float*)d_in[0];
    const int*   ei     = (const int*)d_in[1];
    const float* ea     = (const float*)d_in[2];
    const float* w1_0   = (const float*)d_in[3];
    const float* b1_0   = (const float*)d_in[4];
    const float* w2_0   = (const float*)d_in[5];
    const float* b2_0   = (const float*)d_in[6];
    const float* root_0 = (const float*)d_in[7];
    const float* bias_0 = (const float*)d_in[8];
    const float* w1_1   = (const float*)d_in[9];
    const float* b1_1   = (const float*)d_in[10];
    const float* w2_1   = (const float*)d_in[11];
    const float* b2_1   = (const float*)d_in[12];
    const float* root_1 = (const float*)d_in[13];
    const float* bias_1 = (const float*)d_in[14];
    float* out = (float*)d_out;

    int N = in_sizes[0] / 32;
    int E = in_sizes[1] / 2;
    const int* srcI = ei;
    const int* dstI = ei + E;

    char* ws = (char*)d_ws;
    size_t off = 0;
    auto carve = [&](size_t bytes) {
        void* p = ws + off;
        off += (bytes + 255) & ~(size_t)255;
        return p;
    };
    _Float16* BF0  = (_Float16*)carve((size_t)264 * 512 * 2);
    _Float16* BF1  = (_Float16*)carve((size_t)528 * 512 * 2);
    _Float16* XB0  = (_Float16*)carve((size_t)N * 32 * 2);
    _Float16* X1B  = (_Float16*)carve((size_t)N * 64 * 2);
    float*    AGG0 = (float*)carve((size_t)N * 64 * 4);
    float*    AGG1 = (float*)carve((size_t)N * 64 * 4);

    int tprep = (264 + 528) * 512 + N * 64;
    prep_fused<<<(tprep + 255) / 256, 256, 0, stream>>>(w2_0, b2_0, BF0, w2_1, b2_1, BF1,
                                                        x, root_0, bias_0, AGG0, XB0, N);

    int gblocks = (E + 255) / 256;
    edge_gemm<32><<<gblocks, 512, 0, stream>>>(ea, w1_0, b1_0, XB0, BF0, srcI, dstI, AGG0, E);

    mid_kernel<<<(N * 64 + 255) / 256, 256, 0, stream>>>(AGG0, root_1, bias_1, X1B, AGG1, N);

    edge_gemm<64><<<gblocks, 512, 0, stream>>>(ea, w1_1, b1_1, X1B, BF1, srcI, dstI, AGG1, E);

    final_relu<<<(N * 64 + 255) / 256, 256, 0, stream>>>(AGG1, out, N * 64);
}